// Round 2
// baseline (271.444 us; speedup 1.0000x reference)
//
#include <hip/hip_runtime.h>
#include <hip/hip_bf16.h>
#include <stdint.h>

#define NSK 1000
#define DD 64
#define MM 64
#define BB 64
#define TT 200

// Pass A: per (b,t) row: w = softmax(k·Mk^T), e = sigmoid(v·eW^T+eb), a = tanh(v·aW^T+ab)
// one wave per row; lane j owns output j (weight row j in registers, inputs via shfl broadcast)
__global__ __launch_bounds__(256) void wea_kernel(
    const int* __restrict__ skills, const int* __restrict__ responses,
    const float* __restrict__ k_emb, const float* __restrict__ v_emb,
    const float* __restrict__ Mk, const float* __restrict__ eW,
    const float* __restrict__ eb, const float* __restrict__ aW,
    const float* __restrict__ ab,
    float* __restrict__ w_ws, float* __restrict__ e_ws, float* __restrict__ a_ws)
{
  const int wave = threadIdx.x >> 6;
  const int lane = threadIdx.x & 63;
  const int row  = blockIdx.x * 4 + wave;            // 0..B*T-1 (grid exact)
  const int sk = skills[row];
  int r = responses[row]; r = (r > -1) ? r : 0;      // masked_r
  const int xv = sk + NSK * r;
  const float kv = k_emb[(size_t)sk * DD + lane];
  const float vv = v_emb[(size_t)xv * DD + lane];

  const float4* mk4 = (const float4*)Mk + (size_t)lane * 16;  // 64 f32 = 16 float4 per row
  const float4* ew4 = (const float4*)eW + (size_t)lane * 16;
  const float4* aw4 = (const float4*)aW + (size_t)lane * 16;
  float accK = 0.f, accE = 0.f, accA = 0.f;
  #pragma unroll
  for (int c = 0; c < 16; ++c) {
    float4 qm = mk4[c], qe = ew4[c], qa = aw4[c];
    float mm[4] = {qm.x, qm.y, qm.z, qm.w};
    float ee[4] = {qe.x, qe.y, qe.z, qe.w};
    float aa[4] = {qa.x, qa.y, qa.z, qa.w};
    #pragma unroll
    for (int j = 0; j < 4; ++j) {
      const int d = c * 4 + j;
      float kd = __shfl(kv, d);
      float vd = __shfl(vv, d);
      accK = fmaf(kd, mm[j], accK);
      accE = fmaf(vd, ee[j], accE);
      accA = fmaf(vd, aa[j], accA);
    }
  }
  // wave softmax over the 64 lanes (axis m)
  float mx = accK;
  #pragma unroll
  for (int off = 32; off; off >>= 1) mx = fmaxf(mx, __shfl_xor(mx, off));
  float ex = __expf(accK - mx);
  float sm = ex;
  #pragma unroll
  for (int off = 32; off; off >>= 1) sm += __shfl_xor(sm, off);
  const float wv  = ex / sm;
  const float evv = 1.f / (1.f + __expf(-(accE + eb[lane])));
  const float avv = tanhf(accA + ab[lane]);
  w_ws[(size_t)row * 64 + lane] = wv;
  e_ws[(size_t)row * 64 + lane] = evv;
  a_ws[(size_t)row * 64 + lane] = avv;
}

// Pass B: sequential scan, one block per batch. 4 waves x 16 Mv-rows each, lane = column d.
// read-reduction across waves is DEFERRED to pass C (per-wave partials to scratch) -> no barriers.
__global__ __launch_bounds__(256) void scan_kernel(
    const float* __restrict__ Mv0,
    const float* __restrict__ w_ws, const float* __restrict__ e_ws,
    const float* __restrict__ a_ws, float* __restrict__ part_ws)
{
  const int b    = blockIdx.x;
  const int wave = threadIdx.x >> 6;
  const int lane = threadIdx.x & 63;
  const int m0   = wave * 16;
  float Mv[16];
  #pragma unroll
  for (int i = 0; i < 16; ++i) Mv[i] = Mv0[(size_t)(m0 + i) * DD + lane];

  const float* wr = w_ws + (size_t)b * TT * 64;
  const float* er = e_ws + (size_t)b * TT * 64;
  const float* ar = a_ws + (size_t)b * TT * 64;
  float* pr = part_ws + (size_t)b * TT * 256;

  // software-pipelined per-step loads (lanes 0..15 carry w[m0..m0+15], replicated above)
  float wv = wr[m0 + (lane & 15)];
  float ev = er[lane];
  float av = ar[lane];
  for (int t = 0; t < TT; ++t) {
    float wn = 0.f, en = 0.f, an = 0.f;
    if (t + 1 < TT) {
      wn = wr[(t + 1) * 64 + m0 + (lane & 15)];
      en = er[(t + 1) * 64 + lane];
      an = ar[(t + 1) * 64 + lane];
    }
    float rp = 0.f;
    #pragma unroll
    for (int i = 0; i < 16; ++i) {
      float wm = __shfl(wv, i);            // broadcast w[m0+i]
      rp = fmaf(wm, Mv[i], rp);            // read uses PRE-update Mv
      float tp = fmaf(-ev, Mv[i], av);     // a - e*Mv
      Mv[i] = fmaf(wm, tp, Mv[i]);         // Mv += w*(a - e*Mv)
    }
    pr[t * 256 + wave * 64 + lane] = rp;   // per-wave partial of read[d]
    wv = wn; ev = en; av = an;
  }
}

// Pass C: per (b, t>=1) row: read = sum of 4 partials; f = tanh([read,k]·fW^T + fb);
// p = sigmoid(f·pW + pb); out[b][t-1] = p
__global__ __launch_bounds__(256) void fp_kernel(
    const int* __restrict__ skills, const float* __restrict__ k_emb,
    const float* __restrict__ fW, const float* __restrict__ fb,
    const float* __restrict__ pW, const float* __restrict__ pb,
    const float* __restrict__ part_ws, float* __restrict__ out)
{
  const int wave = threadIdx.x >> 6;
  const int lane = threadIdx.x & 63;
  const int idx  = blockIdx.x * 4 + wave;            // 0..B*(T-1)-1 (grid exact)
  const int b    = idx / (TT - 1);
  const int tm1  = idx % (TT - 1);
  const int row  = b * TT + tm1 + 1;

  const float* pp = part_ws + (size_t)row * 256;
  float rv = pp[lane] + pp[64 + lane] + pp[128 + lane] + pp[192 + lane];
  float kv = k_emb[(size_t)skills[row] * DD + lane];

  const float4* fw4 = (const float4*)fW + (size_t)lane * 32;  // 128 f32 = 32 float4 per row
  float acc = fb[lane];
  #pragma unroll
  for (int c = 0; c < 32; ++c) {
    float4 q = fw4[c];
    float ww[4] = {q.x, q.y, q.z, q.w};
    #pragma unroll
    for (int j = 0; j < 4; ++j) {
      const int i = c * 4 + j;
      float s = (i < 64) ? __shfl(rv, i) : __shfl(kv, i - 64);
      acc = fmaf(s, ww[j], acc);
    }
  }
  float fj = tanhf(acc);
  float prod = fj * pW[lane];
  #pragma unroll
  for (int off = 32; off; off >>= 1) prod += __shfl_xor(prod, off);
  float p = 1.f / (1.f + __expf(-(prod + pb[0])));
  if (lane == 0) out[(size_t)b * (TT - 1) + tm1] = p;
}

extern "C" void kernel_launch(void* const* d_in, const int* in_sizes, int n_in,
                              void* d_out, int out_size, void* d_ws, size_t ws_size,
                              hipStream_t stream) {
  const int* skills    = (const int*)d_in[0];
  const int* responses = (const int*)d_in[1];
  const float* k_emb   = (const float*)d_in[2];
  const float* v_emb   = (const float*)d_in[3];
  const float* Mk      = (const float*)d_in[4];
  const float* Mv0     = (const float*)d_in[5];
  const float* fW      = (const float*)d_in[6];
  const float* fb      = (const float*)d_in[7];
  const float* eW      = (const float*)d_in[8];
  const float* eb      = (const float*)d_in[9];
  const float* aW      = (const float*)d_in[10];
  const float* ab      = (const float*)d_in[11];
  const float* pW      = (const float*)d_in[12];
  const float* pb      = (const float*)d_in[13];

  // fp32 scratch layout: w | e | a (B*T*64 each) | read-partials (B*T*256)  ~= 23 MB
  float* w_ws    = (float*)d_ws;
  float* e_ws    = w_ws + (size_t)BB * TT * 64;
  float* a_ws    = e_ws + (size_t)BB * TT * 64;
  float* part_ws = a_ws + (size_t)BB * TT * 64;

  wea_kernel<<<dim3(BB * TT / 4), 256, 0, stream>>>(
      skills, responses, k_emb, v_emb, Mk, eW, eb, aW, ab, w_ws, e_ws, a_ws);
  scan_kernel<<<dim3(BB), 256, 0, stream>>>(Mv0, w_ws, e_ws, a_ws, part_ws);
  fp_kernel<<<dim3(BB * (TT - 1) / 4), 256, 0, stream>>>(
      skills, k_emb, fW, fb, pW, pb, part_ws, (float*)d_out);
}

// Round 3
// 182.559 us; speedup vs baseline: 1.4869x; 1.4869x over previous
//
#include <hip/hip_runtime.h>
#include <hip/hip_bf16.h>
#include <stdint.h>

#define NSK 1000
#define DD 64
#define MM 64
#define BB 64
#define TT 200

// broadcast lane l's value to all lanes via v_readlane (l compile-time constant)
__device__ __forceinline__ float lane_bcast(float v, int l) {
  return __uint_as_float(__builtin_amdgcn_readlane(__float_as_uint(v), l));
}

// Pass A: per (b,t) row: w = softmax(k·Mk^T), e = sigmoid(v·eW^T+eb), a = tanh(v·aW^T+ab)
// Weights staged in LDS with quad-rotation swizzle: quad (j,c) -> dword j*64 + ((c+j)&15)*4
// so per-lane row reads (ds_read_b128) spread uniformly over all 32 banks (8/bank = floor).
// 16 rows per block (4 per wave) to amortize staging.
__global__ __launch_bounds__(256) void wea_kernel(
    const int* __restrict__ skills, const int* __restrict__ responses,
    const float* __restrict__ k_emb, const float* __restrict__ v_emb,
    const float* __restrict__ Mk, const float* __restrict__ eW,
    const float* __restrict__ eb, const float* __restrict__ aW,
    const float* __restrict__ ab,
    float* __restrict__ w_ws, float* __restrict__ e_ws, float* __restrict__ a_ws)
{
  __shared__ float sMk[4096], seW[4096], saW[4096];
  const int tid = threadIdx.x;
  for (int Q = tid; Q < 1024; Q += 256) {          // 1024 quads per 64x64 matrix
    const int j = Q >> 4, c = Q & 15;
    const int dst = j * 64 + ((c + j) & 15) * 4;
    *(float4*)&sMk[dst] = ((const float4*)Mk)[Q];
    *(float4*)&seW[dst] = ((const float4*)eW)[Q];
    *(float4*)&saW[dst] = ((const float4*)aW)[Q];
  }
  __syncthreads();

  const int wave = tid >> 6, lane = tid & 63;
  const float ebl = eb[lane], abl = ab[lane];

  #pragma unroll 1
  for (int i = 0; i < 4; ++i) {
    const int row = blockIdx.x * 16 + wave * 4 + i;   // grid exact: 800*16 = 12800
    const int sk = skills[row];
    int r = responses[row]; r = (r > -1) ? r : 0;     // masked_r
    const float kv = k_emb[(size_t)sk * DD + lane];
    const float vv = v_emb[(size_t)(sk + NSK * r) * DD + lane];

    float accK = 0.f, accE = 0.f, accA = 0.f;
    #pragma unroll
    for (int c = 0; c < 16; ++c) {
      const int off = lane * 64 + ((c + lane) & 15) * 4;
      float4 qm = *(const float4*)&sMk[off];
      float4 qe = *(const float4*)&seW[off];
      float4 qa = *(const float4*)&saW[off];
      float mm[4] = {qm.x, qm.y, qm.z, qm.w};
      float ee[4] = {qe.x, qe.y, qe.z, qe.w};
      float aa[4] = {qa.x, qa.y, qa.z, qa.w};
      #pragma unroll
      for (int j = 0; j < 4; ++j) {
        const int d = c * 4 + j;
        const float kd = lane_bcast(kv, d);
        const float vd = lane_bcast(vv, d);
        accK = fmaf(kd, mm[j], accK);
        accE = fmaf(vd, ee[j], accE);
        accA = fmaf(vd, aa[j], accA);
      }
    }
    // wave softmax over 64 lanes (axis m)
    float mx = accK;
    #pragma unroll
    for (int off = 32; off; off >>= 1) mx = fmaxf(mx, __shfl_xor(mx, off));
    float ex = __expf(accK - mx);
    float sm = ex;
    #pragma unroll
    for (int off = 32; off; off >>= 1) sm += __shfl_xor(sm, off);
    const float wv  = ex / sm;
    const float evv = 1.f / (1.f + __expf(-(accE + ebl)));
    const float avv = tanhf(accA + abl);
    w_ws[(size_t)row * 64 + lane] = wv;
    e_ws[(size_t)row * 64 + lane] = evv;
    a_ws[(size_t)row * 64 + lane] = avv;
  }
}

// Pass B: sequential scan, one block per batch. 4 waves x 16 Mv-rows each, lane = column d.
// read-reduction across waves is DEFERRED to pass C (per-wave partials) -> no barriers.
__global__ __launch_bounds__(256) void scan_kernel(
    const float* __restrict__ Mv0,
    const float* __restrict__ w_ws, const float* __restrict__ e_ws,
    const float* __restrict__ a_ws, float* __restrict__ part_ws)
{
  const int b    = blockIdx.x;
  const int wave = threadIdx.x >> 6;
  const int lane = threadIdx.x & 63;
  const int m0   = wave * 16;
  float Mv[16];
  #pragma unroll
  for (int i = 0; i < 16; ++i) Mv[i] = Mv0[(size_t)(m0 + i) * DD + lane];

  const float* wr = w_ws + (size_t)b * TT * 64;
  const float* er = e_ws + (size_t)b * TT * 64;
  const float* ar = a_ws + (size_t)b * TT * 64;
  float* pr = part_ws + (size_t)b * TT * 256;

  float wv = wr[m0 + (lane & 15)];
  float ev = er[lane];
  float av = ar[lane];
  for (int t = 0; t < TT; ++t) {
    float wn = 0.f, en = 0.f, an = 0.f;
    if (t + 1 < TT) {
      wn = wr[(t + 1) * 64 + m0 + (lane & 15)];
      en = er[(t + 1) * 64 + lane];
      an = ar[(t + 1) * 64 + lane];
    }
    float rp = 0.f;
    #pragma unroll
    for (int i = 0; i < 16; ++i) {
      float wm = lane_bcast(wv, i);        // w[m0+i] sits in lane i (0..15)
      rp = fmaf(wm, Mv[i], rp);            // read uses PRE-update Mv
      float tp = fmaf(-ev, Mv[i], av);     // a - e*Mv
      Mv[i] = fmaf(wm, tp, Mv[i]);         // Mv += w*(a - e*Mv)
    }
    pr[t * 256 + wave * 64 + lane] = rp;   // per-wave partial of read[d]
    wv = wn; ev = en; av = an;
  }
}

// Pass C: per (b, t>=1) row: read = sum of 4 partials; f = tanh([read,k]·fW^T + fb);
// p = sigmoid(f·pW + pb). fW rows are 128 dwords: quad (j,c) -> dword j*128 + ((c+j)&31)*4.
__global__ __launch_bounds__(256) void fp_kernel(
    const int* __restrict__ skills, const float* __restrict__ k_emb,
    const float* __restrict__ fW, const float* __restrict__ fb,
    const float* __restrict__ pW, const float* __restrict__ pb,
    const float* __restrict__ part_ws, float* __restrict__ out)
{
  __shared__ float sfW[8192];
  const int tid = threadIdx.x;
  for (int Q = tid; Q < 2048; Q += 256) {          // 2048 quads in 64x128 fW
    const int j = Q >> 5, c = Q & 31;
    *(float4*)&sfW[j * 128 + ((c + j) & 31) * 4] = ((const float4*)fW)[Q];
  }
  __syncthreads();

  const int wave = tid >> 6, lane = tid & 63;
  const float fbl = fb[lane];
  const float pwl = pW[lane];
  const float pb0 = pb[0];

  #pragma unroll 1
  for (int i = 0; i < 4; ++i) {
    const int idx = blockIdx.x * 16 + wave * 4 + i;  // grid exact: 796*16 = 12736
    const int b   = idx / (TT - 1);
    const int tm1 = idx % (TT - 1);
    const int row = b * TT + tm1 + 1;

    const float* pp = part_ws + (size_t)row * 256;
    float rv = pp[lane] + pp[64 + lane] + pp[128 + lane] + pp[192 + lane];
    float kv = k_emb[(size_t)skills[row] * DD + lane];

    float acc = fbl;
    #pragma unroll
    for (int c = 0; c < 32; ++c) {
      const int off = lane * 128 + ((c + lane) & 31) * 4;
      float4 q = *(const float4*)&sfW[off];
      float ww[4] = {q.x, q.y, q.z, q.w};
      #pragma unroll
      for (int j = 0; j < 4; ++j) {
        const int d = c * 4 + j;
        const float s = (d < 64) ? lane_bcast(rv, d) : lane_bcast(kv, d - 64);
        acc = fmaf(s, ww[j], acc);
      }
    }
    float fj = tanhf(acc);
    float prod = fj * pwl;
    #pragma unroll
    for (int off = 32; off; off >>= 1) prod += __shfl_xor(prod, off);
    float p = 1.f / (1.f + __expf(-(prod + pb0)));
    if (lane == 0) out[(size_t)b * (TT - 1) + tm1] = p;
  }
}

extern "C" void kernel_launch(void* const* d_in, const int* in_sizes, int n_in,
                              void* d_out, int out_size, void* d_ws, size_t ws_size,
                              hipStream_t stream) {
  const int* skills    = (const int*)d_in[0];
  const int* responses = (const int*)d_in[1];
  const float* k_emb   = (const float*)d_in[2];
  const float* v_emb   = (const float*)d_in[3];
  const float* Mk      = (const float*)d_in[4];
  const float* Mv0     = (const float*)d_in[5];
  const float* fW      = (const float*)d_in[6];
  const float* fb      = (const float*)d_in[7];
  const float* eW      = (const float*)d_in[8];
  const float* eb      = (const float*)d_in[9];
  const float* aW      = (const float*)d_in[10];
  const float* ab      = (const float*)d_in[11];
  const float* pW      = (const float*)d_in[12];
  const float* pb      = (const float*)d_in[13];

  // fp32 scratch layout: w | e | a (B*T*64 each) | read-partials (B*T*256)  ~= 23 MB
  float* w_ws    = (float*)d_ws;
  float* e_ws    = w_ws + (size_t)BB * TT * 64;
  float* a_ws    = e_ws + (size_t)BB * TT * 64;
  float* part_ws = a_ws + (size_t)BB * TT * 64;

  wea_kernel<<<dim3(BB * TT / 16), 256, 0, stream>>>(
      skills, responses, k_emb, v_emb, Mk, eW, eb, aW, ab, w_ws, e_ws, a_ws);
  scan_kernel<<<dim3(BB), 256, 0, stream>>>(Mv0, w_ws, e_ws, a_ws, part_ws);
  fp_kernel<<<dim3(BB * (TT - 1) / 16), 256, 0, stream>>>(
      skills, k_emb, fW, fb, pW, pb, part_ws, (float*)d_out);
}

// Round 4
// 146.513 us; speedup vs baseline: 1.8527x; 1.2460x over previous
//
#include <hip/hip_runtime.h>
#include <hip/hip_bf16.h>
#include <stdint.h>

#define NSK 1000
#define DD 64
#define MM 64
#define BB 64
#define TT 200

// broadcast lane l's value to all lanes via v_readlane (l compile-time constant)
__device__ __forceinline__ float lane_bcast(float v, int l) {
  return __uint_as_float(__builtin_amdgcn_readlane(__float_as_uint(v), l));
}

// Pass A: per (b,t) row: w = softmax(k·Mk^T), e = sigmoid(v·eW^T+eb), a = tanh(v·aW^T+ab)
// Weights staged in LDS with quad-rotation swizzle: quad (j,c) -> dword j*64 + ((c+j)&15)*4
// so per-lane row reads (ds_read_b128) spread uniformly over all 32 banks (8/bank = floor).
__global__ __launch_bounds__(256) void wea_kernel(
    const int* __restrict__ skills, const int* __restrict__ responses,
    const float* __restrict__ k_emb, const float* __restrict__ v_emb,
    const float* __restrict__ Mk, const float* __restrict__ eW,
    const float* __restrict__ eb, const float* __restrict__ aW,
    const float* __restrict__ ab,
    float* __restrict__ w_ws, float* __restrict__ e_ws, float* __restrict__ a_ws)
{
  __shared__ float sMk[4096], seW[4096], saW[4096];
  const int tid = threadIdx.x;
  for (int Q = tid; Q < 1024; Q += 256) {          // 1024 quads per 64x64 matrix
    const int j = Q >> 4, c = Q & 15;
    const int dst = j * 64 + ((c + j) & 15) * 4;
    *(float4*)&sMk[dst] = ((const float4*)Mk)[Q];
    *(float4*)&seW[dst] = ((const float4*)eW)[Q];
    *(float4*)&saW[dst] = ((const float4*)aW)[Q];
  }
  __syncthreads();

  const int wave = tid >> 6, lane = tid & 63;
  const float ebl = eb[lane], abl = ab[lane];

  // issue all 4 rows' gather chains up-front (4 independent chains in flight)
  float kvs[4], vvs[4];
  #pragma unroll
  for (int i = 0; i < 4; ++i) {
    const int row = blockIdx.x * 16 + wave * 4 + i;
    const int sk = skills[row];
    int r = responses[row]; r = (r > -1) ? r : 0;   // masked_r
    kvs[i] = k_emb[(size_t)sk * DD + lane];
    vvs[i] = v_emb[(size_t)(sk + NSK * r) * DD + lane];
  }

  #pragma unroll 1
  for (int i = 0; i < 4; ++i) {
    const int row = blockIdx.x * 16 + wave * 4 + i;   // grid exact: 800*16 = 12800
    const float kv = kvs[i], vv = vvs[i];

    float accK = 0.f, accE = 0.f, accA = 0.f;
    #pragma unroll
    for (int c = 0; c < 16; ++c) {
      const int off = lane * 64 + ((c + lane) & 15) * 4;
      float4 qm = *(const float4*)&sMk[off];
      float4 qe = *(const float4*)&seW[off];
      float4 qa = *(const float4*)&saW[off];
      float mm[4] = {qm.x, qm.y, qm.z, qm.w};
      float ee[4] = {qe.x, qe.y, qe.z, qe.w};
      float aa[4] = {qa.x, qa.y, qa.z, qa.w};
      #pragma unroll
      for (int j = 0; j < 4; ++j) {
        const int d = c * 4 + j;
        const float kd = lane_bcast(kv, d);
        const float vd = lane_bcast(vv, d);
        accK = fmaf(kd, mm[j], accK);
        accE = fmaf(vd, ee[j], accE);
        accA = fmaf(vd, aa[j], accA);
      }
    }
    // wave softmax over 64 lanes (axis m)
    float mx = accK;
    #pragma unroll
    for (int off = 32; off; off >>= 1) mx = fmaxf(mx, __shfl_xor(mx, off));
    float ex = __expf(accK - mx);
    float sm = ex;
    #pragma unroll
    for (int off = 32; off; off >>= 1) sm += __shfl_xor(sm, off);
    const float wv  = ex / sm;
    const float evv = 1.f / (1.f + __expf(-(accE + ebl)));
    const float avv = tanhf(accA + abl);
    w_ws[(size_t)row * 64 + lane] = wv;
    e_ws[(size_t)row * 64 + lane] = evv;
    a_ws[(size_t)row * 64 + lane] = avv;
  }
}

// ---- scan helpers: chunked register double-buffer (depth CH=8 steps) ----
#define CH 8

__device__ __forceinline__ void load_chunk(
    const float* __restrict__ wr, const float* __restrict__ er,
    const float* __restrict__ ar, int t0, int wl, int lane,
    float* wb, float* ebf, float* abf)
{
  #pragma unroll
  for (int k = 0; k < CH; ++k) {
    wb[k]  = wr[(t0 + k) * 64 + wl];
    ebf[k] = er[(t0 + k) * 64 + lane];
    abf[k] = ar[(t0 + k) * 64 + lane];
  }
}

__device__ __forceinline__ void compute_chunk(
    float* Mv, const float* wb, const float* ebf, const float* abf,
    int t0, int wave, int lane, float* __restrict__ pr)
{
  #pragma unroll
  for (int k = 0; k < CH; ++k) {
    const float wv = wb[k], ev = ebf[k], av = abf[k];
    float rp = 0.f;
    #pragma unroll
    for (int i = 0; i < 16; ++i) {
      float wm = lane_bcast(wv, i);        // w[m0+i] sits in lane i (0..15)
      rp = fmaf(wm, Mv[i], rp);            // read uses PRE-update Mv
      float tp = fmaf(-ev, Mv[i], av);     // a - e*Mv
      Mv[i] = fmaf(wm, tp, Mv[i]);         // Mv += w*(a - e*Mv)
    }
    pr[(t0 + k) * 256 + wave * 64 + lane] = rp;  // per-wave partial of read[d]
  }
}

// Pass B: sequential scan, one block per batch. 4 waves x 16 Mv-rows each, lane = column d.
// read-reduction across waves DEFERRED to pass C. 8-step register double-buffer so ~24
// loads stay in flight across each ~1100-cyc compute chunk (covers ~900-cyc HBM latency).
__global__ __launch_bounds__(256) void scan_kernel(
    const float* __restrict__ Mv0,
    const float* __restrict__ w_ws, const float* __restrict__ e_ws,
    const float* __restrict__ a_ws, float* __restrict__ part_ws)
{
  const int b    = blockIdx.x;
  const int wave = threadIdx.x >> 6;
  const int lane = threadIdx.x & 63;
  const int m0   = wave * 16;
  const int wl   = m0 + (lane & 15);
  float Mv[16];
  #pragma unroll
  for (int i = 0; i < 16; ++i) Mv[i] = Mv0[(size_t)(m0 + i) * DD + lane];

  const float* wr = w_ws + (size_t)b * TT * 64;
  const float* er = e_ws + (size_t)b * TT * 64;
  const float* ar = a_ws + (size_t)b * TT * 64;
  float* pr = part_ws + (size_t)b * TT * 256;

  float wb0[CH], eb0[CH], ab0[CH];
  float wb1[CH], eb1[CH], ab1[CH];
  load_chunk(wr, er, ar, 0, wl, lane, wb0, eb0, ab0);

  // TT/CH = 25 chunks; manual 2-unroll so buffer selection is compile-time
  for (int ch = 0; ch < TT / CH; ch += 2) {
    if ((ch + 1) * CH < TT)
      load_chunk(wr, er, ar, (ch + 1) * CH, wl, lane, wb1, eb1, ab1);
    compute_chunk(Mv, wb0, eb0, ab0, ch * CH, wave, lane, pr);
    if ((ch + 2) * CH < TT)
      load_chunk(wr, er, ar, (ch + 2) * CH, wl, lane, wb0, eb0, ab0);
    if ((ch + 1) * CH < TT)
      compute_chunk(Mv, wb1, eb1, ab1, (ch + 1) * CH, wave, lane, pr);
  }
}

// Pass C: per (b, t>=1) row: read = sum of 4 partials; f = tanh([read,k]·fW^T + fb);
// p = sigmoid(f·pW + pb). fW rows are 128 dwords: quad (j,c) -> dword j*128 + ((c+j)&31)*4.
__global__ __launch_bounds__(256) void fp_kernel(
    const int* __restrict__ skills, const float* __restrict__ k_emb,
    const float* __restrict__ fW, const float* __restrict__ fb,
    const float* __restrict__ pW, const float* __restrict__ pb,
    const float* __restrict__ part_ws, float* __restrict__ out)
{
  __shared__ float sfW[8192];
  const int tid = threadIdx.x;
  for (int Q = tid; Q < 2048; Q += 256) {          // 2048 quads in 64x128 fW
    const int j = Q >> 5, c = Q & 31;
    *(float4*)&sfW[j * 128 + ((c + j) & 31) * 4] = ((const float4*)fW)[Q];
  }
  __syncthreads();

  const int wave = tid >> 6, lane = tid & 63;
  const float fbl = fb[lane];
  const float pwl = pW[lane];
  const float pb0 = pb[0];

  // issue all 4 rows' loads up-front (20 loads in flight)
  float rvs[4], kvs[4];
  #pragma unroll
  for (int i = 0; i < 4; ++i) {
    const int idx = blockIdx.x * 16 + wave * 4 + i;
    const int b   = idx / (TT - 1);
    const int tm1 = idx % (TT - 1);
    const int row = b * TT + tm1 + 1;
    const float* pp = part_ws + (size_t)row * 256;
    rvs[i] = (pp[lane] + pp[64 + lane]) + (pp[128 + lane] + pp[192 + lane]);
    kvs[i] = k_emb[(size_t)skills[row] * DD + lane];
  }

  #pragma unroll 1
  for (int i = 0; i < 4; ++i) {
    const int idx = blockIdx.x * 16 + wave * 4 + i;  // grid exact: 796*16 = 12736
    const int b   = idx / (TT - 1);
    const int tm1 = idx % (TT - 1);
    const float rv = rvs[i], kv = kvs[i];

    float acc = fbl;
    #pragma unroll
    for (int c = 0; c < 32; ++c) {
      const int off = lane * 128 + ((c + lane) & 31) * 4;
      float4 q = *(const float4*)&sfW[off];
      float ww[4] = {q.x, q.y, q.z, q.w};
      #pragma unroll
      for (int j = 0; j < 4; ++j) {
        const int d = c * 4 + j;
        const float s = (d < 64) ? lane_bcast(rv, d) : lane_bcast(kv, d - 64);
        acc = fmaf(s, ww[j], acc);
      }
    }
    float fj = tanhf(acc);
    float prod = fj * pwl;
    #pragma unroll
    for (int off = 32; off; off >>= 1) prod += __shfl_xor(prod, off);
    float p = 1.f / (1.f + __expf(-(prod + pb0)));
    if (lane == 0) out[(size_t)b * (TT - 1) + tm1] = p;
  }
}

extern "C" void kernel_launch(void* const* d_in, const int* in_sizes, int n_in,
                              void* d_out, int out_size, void* d_ws, size_t ws_size,
                              hipStream_t stream) {
  const int* skills    = (const int*)d_in[0];
  const int* responses = (const int*)d_in[1];
  const float* k_emb   = (const float*)d_in[2];
  const float* v_emb   = (const float*)d_in[3];
  const float* Mk      = (const float*)d_in[4];
  const float* Mv0     = (const float*)d_in[5];
  const float* fW      = (const float*)d_in[6];
  const float* fb      = (const float*)d_in[7];
  const float* eW      = (const float*)d_in[8];
  const float* eb      = (const float*)d_in[9];
  const float* aW      = (const float*)d_in[10];
  const float* ab      = (const float*)d_in[11];
  const float* pW      = (const float*)d_in[12];
  const float* pb      = (const float*)d_in[13];

  // fp32 scratch layout: w | e | a (B*T*64 each) | read-partials (B*T*256)  ~= 23 MB
  float* w_ws    = (float*)d_ws;
  float* e_ws    = w_ws + (size_t)BB * TT * 64;
  float* a_ws    = e_ws + (size_t)BB * TT * 64;
  float* part_ws = a_ws + (size_t)BB * TT * 64;

  wea_kernel<<<dim3(BB * TT / 16), 256, 0, stream>>>(
      skills, responses, k_emb, v_emb, Mk, eW, eb, aW, ab, w_ws, e_ws, a_ws);
  scan_kernel<<<dim3(BB), 256, 0, stream>>>(Mv0, w_ws, e_ws, a_ws, part_ws);
  fp_kernel<<<dim3(BB * (TT - 1) / 16), 256, 0, stream>>>(
      skills, k_emb, fW, fb, pW, pb, part_ws, (float*)d_out);
}